// Round 1
// baseline (1107.640 us; speedup 1.0000x reference)
//
#include <hip/hip_runtime.h>
#include <math.h>

#define N_ATOMS 3072
#define C_Ac 128
#define C_Sc 384
#define C_Zc 16
#define QT 64          // queries per attention block
#define KC 16          // flash-decoding splits
#define CHUNK (N_ATOMS/KC)   // 192 keys per chunk
#define KT 8           // keys per sub-tile
#define NST (CHUNK/KT)       // 24 sub-tiles per block
#define NQT (N_ATOMS/QT)     // 48 q-tiles

__device__ __forceinline__ float sigm(float x){ return 1.f/(1.f+__expf(-x)); }

// ---------------- Stage A: AdaLN1 + QKV/G projections (4 rows/block) ----------------
__global__ __launch_bounds__(256) void k_stage_a(
    const float* __restrict__ a, const float* __restrict__ s,
    const float* __restrict__ s_w, const float* __restrict__ scale_w,
    const float* __restrict__ scale_b, const float* __restrict__ shift_w,
    const float* __restrict__ wq, const float* __restrict__ bq,
    const float* __restrict__ wk, const float* __restrict__ wv,
    const float* __restrict__ wg,
    float* __restrict__ qo, float* __restrict__ ko, float* __restrict__ vo,
    float* __restrict__ go, float* __restrict__ lns)
{
  __shared__ float sn[4][C_Sc];
  __shared__ float an[4][C_Ac];
  __shared__ float hsh[4][C_Ac];
  __shared__ float t1[4][C_Ac], t2[4][C_Ac];
  int n0 = blockIdx.x*4;
  int tid = threadIdx.x, w = tid>>6, lane = tid&63;

  { // LN(s), row = wave
    const float* srow = s + (size_t)(n0+w)*C_Sc;
    float v[6]; float sx=0.f, sxx=0.f;
    #pragma unroll
    for (int j=0;j<6;j++){ v[j]=srow[lane+j*64]; sx+=v[j]; sxx+=v[j]*v[j]; }
    #pragma unroll
    for (int off=32;off;off>>=1){ sx+=__shfl_xor(sx,off,64); sxx+=__shfl_xor(sxx,off,64); }
    float mean=sx*(1.f/C_Sc), rs=rsqrtf(sxx*(1.f/C_Sc)-mean*mean+1e-5f);
    #pragma unroll
    for (int j=0;j<6;j++){
      int i=lane+j*64;
      float ln=(v[j]-mean)*rs;
      lns[(size_t)(n0+w)*C_Sc+i]=ln;
      sn[w][i]=ln*s_w[i];
    }
  }
  { // LN(a), row = wave
    const float* arow = a + (size_t)(n0+w)*C_Ac;
    float v0=arow[lane], v1=arow[lane+64];
    float sx=v0+v1, sxx=v0*v0+v1*v1;
    #pragma unroll
    for (int off=32;off;off>>=1){ sx+=__shfl_xor(sx,off,64); sxx+=__shfl_xor(sxx,off,64); }
    float mean=sx*(1.f/C_Ac), rs=rsqrtf(sxx*(1.f/C_Ac)-mean*mean+1e-5f);
    an[w][lane]=(v0-mean)*rs; an[w][lane+64]=(v1-mean)*rs;
  }
  __syncthreads();

  { // AdaLN1 matmuls: sel0 -> sigmoid(scale), sel1 -> shift
    int c = tid&127, sel = tid>>7;
    const float* W = sel ? shift_w : scale_w;
    float acc[4];
    #pragma unroll
    for (int r=0;r<4;r++) acc[r] = sel ? 0.f : scale_b[c];
    for (int i=0;i<C_Sc;i++){
      float wv = W[(size_t)i*C_Ac+c];
      #pragma unroll
      for (int r=0;r<4;r++) acc[r] += sn[r][i]*wv;
    }
    if (sel==0){ t1[0][c]=sigm(acc[0]); t1[1][c]=sigm(acc[1]); t1[2][c]=sigm(acc[2]); t1[3][c]=sigm(acc[3]); }
    else       { t2[0][c]=acc[0]; t2[1][c]=acc[1]; t2[2][c]=acc[2]; t2[3][c]=acc[3]; }
  }
  __syncthreads();
  for (int f=tid; f<512; f+=256){ int r=f>>7, c=f&127; hsh[r][c] = t1[r][c]*an[r][c] + t2[r][c]; }
  __syncthreads();

  { // QKVG: sel0 -> (q,k), sel1 -> (v,g)
    int c = tid&127, sel = tid>>7;
    const float* Wa = sel ? wv : wq;
    const float* Wb = sel ? wg : wk;
    float accA[4], accB[4];
    #pragma unroll
    for (int r=0;r<4;r++){ accA[r] = sel ? 0.f : bq[c]; accB[r]=0.f; }
    for (int i=0;i<C_Ac;i++){
      float wa=Wa[(size_t)i*C_Ac+c], wb_=Wb[(size_t)i*C_Ac+c];
      #pragma unroll
      for (int r=0;r<4;r++){ float hv=hsh[r][i]; accA[r]+=hv*wa; accB[r]+=hv*wb_; }
    }
    #pragma unroll
    for (int r=0;r<4;r++){
      size_t idx = (size_t)(n0+r)*C_Ac + c;
      if (sel==0){ qo[idx]=accA[r]; ko[idx]=accB[r]; }
      else       { vo[idx]=accA[r]; go[idx]=sigm(accB[r]); }
    }
  }
}

// ---------------- Stage B: flash-decoding attention with fused z bias ----------------
// Redesign: z prefetched one sub-tile ahead into registers (issue-early/write-late),
// K/V staged into LDS so the main loop is vmem-free (keeps z prefetch in flight),
// raw s_barrier + lgkmcnt(0) (no __syncthreads vmcnt(0) drain),
// deferred per-tile softmax (one max/rescale per 8 keys).
__global__ __launch_bounds__(256) void k_attn(
    const float* __restrict__ z, const float* __restrict__ ln_z_w,
    const float* __restrict__ ln_z_b, const float* __restrict__ wb,
    const float* __restrict__ qws, const float* __restrict__ kws,
    const float* __restrict__ vws,
    float* __restrict__ part_m, float* __restrict__ part_l,
    float* __restrict__ part_o)
{
  __shared__ float bias[4][QT][KT+1];     // 9216 B
  __shared__ float ks[KT][C_Ac];          // 4 KB
  __shared__ float vs[KT][C_Ac];          // 4 KB
  __shared__ float lwb_s[C_Zc][4];        // ln_z_w folded into wb
  __shared__ float csum_s[4], bb_s[4];    // column sums, ln_z_b folded

  int qt = blockIdx.x, chunk = blockIdx.y;
  int q0 = qt*QT, k_base = chunk*CHUNK;
  int tid = threadIdx.x, w = tid>>6, lane = tid&63;

  if (tid < 64){ int c = tid>>2, h = tid&3; lwb_s[c][h] = ln_z_w[c]*wb[c*4+h]; }
  if (tid < 4){
    float cs=0.f, bbv=0.f;
    #pragma unroll
    for (int c=0;c<C_Zc;c++){ cs += ln_z_w[c]*wb[c*4+tid]; bbv += ln_z_b[c]*wb[c*4+tid]; }
    csum_s[tid]=cs; bb_s[tid]=bbv;
  }
  __syncthreads();   // full sync BEFORE any prefetch is issued (keeps prefetch undrained)

  // persistent per-thread state
  float qv[32];
  {
    const float4* qp = (const float4*)(qws + (size_t)(q0+lane)*C_Ac + w*32);
    #pragma unroll
    for (int j=0;j<8;j++){ float4 t=qp[j]; qv[4*j]=t.x; qv[4*j+1]=t.y; qv[4*j+2]=t.z; qv[4*j+3]=t.w; }
  }
  float m=-INFINITY, l=0.f, o[32];
  #pragma unroll
  for (int j=0;j<32;j++) o[j]=0.f;
  const float isd = 0.17677669529663687f;

  // prefetch registers: z for 2 (q,k) pairs + this thread's K/V float4
  float z0[16], z1[16];
  float4 kreg, vreg;
  const int qla = (tid>>3), qlb = 32 + (tid>>3), klz = tid&7;

  { // prologue: load sub-tile 0
    int k0n = k_base;
    const float4* zp0 = (const float4*)(z + ((size_t)(q0+qla)*N_ATOMS + (k0n+klz))*C_Zc);
    const float4* zp1 = (const float4*)(z + ((size_t)(q0+qlb)*N_ATOMS + (k0n+klz))*C_Zc);
    #pragma unroll
    for (int j=0;j<4;j++){ float4 t=zp0[j]; z0[4*j]=t.x; z0[4*j+1]=t.y; z0[4*j+2]=t.z; z0[4*j+3]=t.w; }
    #pragma unroll
    for (int j=0;j<4;j++){ float4 t=zp1[j]; z1[4*j]=t.x; z1[4*j+1]=t.y; z1[4*j+2]=t.z; z1[4*j+3]=t.w; }
    kreg = ((const float4*)(kws + (size_t)(k0n + (tid>>5))*C_Ac))[tid&31];
    vreg = ((const float4*)(vws + (size_t)(k0n + (tid>>5))*C_Ac))[tid&31];
  }

  #pragma unroll 1
  for (int st=0; st<NST; st++){
    // ---- step1: stage K/V + bias(st) into LDS from prefetched registers ----
    ((float4*)ks)[tid] = kreg;
    ((float4*)vs)[tid] = vreg;
    { // pair a
      float sum=0.f, ssq=0.f;
      #pragma unroll
      for (int c=0;c<16;c++){ sum+=z0[c]; ssq+=z0[c]*z0[c]; }
      float mz=sum*(1.f/16), rz=rsqrtf(ssq*(1.f/16)-mz*mz+1e-5f);
      float d0=0.f,d1=0.f,d2=0.f,d3=0.f;
      #pragma unroll
      for (int c=0;c<16;c++){ float zc=z0[c];
        d0=fmaf(zc,lwb_s[c][0],d0); d1=fmaf(zc,lwb_s[c][1],d1);
        d2=fmaf(zc,lwb_s[c][2],d2); d3=fmaf(zc,lwb_s[c][3],d3); }
      bias[0][qla][klz]=rz*(d0-mz*csum_s[0])+bb_s[0];
      bias[1][qla][klz]=rz*(d1-mz*csum_s[1])+bb_s[1];
      bias[2][qla][klz]=rz*(d2-mz*csum_s[2])+bb_s[2];
      bias[3][qla][klz]=rz*(d3-mz*csum_s[3])+bb_s[3];
    }
    { // pair b
      float sum=0.f, ssq=0.f;
      #pragma unroll
      for (int c=0;c<16;c++){ sum+=z1[c]; ssq+=z1[c]*z1[c]; }
      float mz=sum*(1.f/16), rz=rsqrtf(ssq*(1.f/16)-mz*mz+1e-5f);
      float d0=0.f,d1=0.f,d2=0.f,d3=0.f;
      #pragma unroll
      for (int c=0;c<16;c++){ float zc=z1[c];
        d0=fmaf(zc,lwb_s[c][0],d0); d1=fmaf(zc,lwb_s[c][1],d1);
        d2=fmaf(zc,lwb_s[c][2],d2); d3=fmaf(zc,lwb_s[c][3],d3); }
      bias[0][qlb][klz]=rz*(d0-mz*csum_s[0])+bb_s[0];
      bias[1][qlb][klz]=rz*(d1-mz*csum_s[1])+bb_s[1];
      bias[2][qlb][klz]=rz*(d2-mz*csum_s[2])+bb_s[2];
      bias[3][qlb][klz]=rz*(d3-mz*csum_s[3])+bb_s[3];
    }
    // ---- step2: issue loads for st+1 (hidden under step4's compute) ----
    if (st+1 < NST){
      int k0n = k_base + (st+1)*KT;
      const float4* zp0 = (const float4*)(z + ((size_t)(q0+qla)*N_ATOMS + (k0n+klz))*C_Zc);
      const float4* zp1 = (const float4*)(z + ((size_t)(q0+qlb)*N_ATOMS + (k0n+klz))*C_Zc);
      #pragma unroll
      for (int j=0;j<4;j++){ float4 t=zp0[j]; z0[4*j]=t.x; z0[4*j+1]=t.y; z0[4*j+2]=t.z; z0[4*j+3]=t.w; }
      #pragma unroll
      for (int j=0;j<4;j++){ float4 t=zp1[j]; z1[4*j]=t.x; z1[4*j+1]=t.y; z1[4*j+2]=t.z; z1[4*j+3]=t.w; }
      kreg = ((const float4*)(kws + (size_t)(k0n + (tid>>5))*C_Ac))[tid&31];
      vreg = ((const float4*)(vws + (size_t)(k0n + (tid>>5))*C_Ac))[tid&31];
    }
    // ---- step3: bias/KV visible to all waves; vmem prefetch stays in flight ----
    asm volatile("s_waitcnt lgkmcnt(0)" ::: "memory");
    __builtin_amdgcn_s_barrier();
    // ---- step4: 8-key tile, deferred softmax; vmem-free ----
    float lg[KT];
    #pragma unroll
    for (int kl=0;kl<KT;kl++) lg[kl] = bias[w][lane][kl];
    #pragma unroll
    for (int kl=0;kl<KT;kl++){
      const float4* kp = (const float4*)&ks[kl][w*32];
      float d0=0.f,d1=0.f,d2=0.f,d3=0.f;
      #pragma unroll
      for (int j=0;j<8;j++){ float4 t=kp[j];
        d0=fmaf(qv[4*j],t.x,d0); d1=fmaf(qv[4*j+1],t.y,d1);
        d2=fmaf(qv[4*j+2],t.z,d2); d3=fmaf(qv[4*j+3],t.w,d3); }
      lg[kl] = fmaf((d0+d1)+(d2+d3), isd, lg[kl]);
    }
    float tm = fmaxf(fmaxf(fmaxf(lg[0],lg[1]),fmaxf(lg[2],lg[3])),
                     fmaxf(fmaxf(lg[4],lg[5]),fmaxf(lg[6],lg[7])));
    float mn = fmaxf(m, tm);
    float ef = __expf(m-mn);
    float ssum = 0.f;
    #pragma unroll
    for (int kl=0;kl<KT;kl++){ float e=__expf(lg[kl]-mn); lg[kl]=e; ssum+=e; }
    l = l*ef + ssum; m = mn;
    #pragma unroll
    for (int j=0;j<32;j++) o[j]*=ef;
    #pragma unroll
    for (int kl=0;kl<KT;kl++){
      const float4* vp = (const float4*)&vs[kl][w*32];
      float e = lg[kl];
      #pragma unroll
      for (int j=0;j<8;j++){ float4 t=vp[j];
        o[4*j]  =fmaf(e,t.x,o[4*j]);   o[4*j+1]=fmaf(e,t.y,o[4*j+1]);
        o[4*j+2]=fmaf(e,t.z,o[4*j+2]); o[4*j+3]=fmaf(e,t.w,o[4*j+3]); }
    }
    // ---- step5: LDS consumed; safe to overwrite next iteration ----
    asm volatile("s_waitcnt lgkmcnt(0)" ::: "memory");
    __builtin_amdgcn_s_barrier();
  }

  // write partials
  size_t pb = (((size_t)chunk*NQT + qt)*4 + w)*64 + lane;
  part_m[pb]=m; part_l[pb]=l;
  float4* po = (float4*)(part_o + pb*32);
  #pragma unroll
  for (int j=0;j<8;j++){ po[j] = make_float4(o[4*j],o[4*j+1],o[4*j+2],o[4*j+3]); }
}

// ---------------- Stage B2: combine partials + gate ----------------
__global__ __launch_bounds__(256) void k_combine(
    const float* __restrict__ part_m, const float* __restrict__ part_l,
    const float* __restrict__ part_o, const float* __restrict__ gws,
    float* __restrict__ gows)
{
  int qt = blockIdx.x, h = blockIdx.y;
  int tid = threadIdx.x, ql = tid&63, dg = tid>>6;
  float mc[KC], lc[KC], M=-INFINITY;
  #pragma unroll
  for (int c=0;c<KC;c++){
    size_t pb = (((size_t)c*NQT + qt)*4 + h)*64 + ql;
    mc[c]=part_m[pb]; lc[c]=part_l[pb]; M=fmaxf(M,mc[c]);
  }
  float L=0.f, oa[8];
  #pragma unroll
  for (int j=0;j<8;j++) oa[j]=0.f;
  #pragma unroll
  for (int c=0;c<KC;c++){
    float sc=__expf(mc[c]-M);
    L += lc[c]*sc;
    const float4* po = (const float4*)(part_o + ((((size_t)c*NQT + qt)*4 + h)*64 + ql)*32 + dg*8);
    float4 t0=po[0], t1=po[1];
    oa[0]+=sc*t0.x; oa[1]+=sc*t0.y; oa[2]+=sc*t0.z; oa[3]+=sc*t0.w;
    oa[4]+=sc*t1.x; oa[5]+=sc*t1.y; oa[6]+=sc*t1.z; oa[7]+=sc*t1.w;
  }
  float invL = 1.f/L;
  size_t base = (size_t)(qt*64+ql)*C_Ac + h*32 + dg*8;
  #pragma unroll
  for (int j=0;j<8;j++) gows[base+j] = gws[base+j]*oa[j]*invL;
}

// ---------------- Stage C: out-proj + gates + transition (4 rows/block) ----------------
__global__ __launch_bounds__(256) void k_stage_c(
    const float* __restrict__ gows, const float* __restrict__ wo,
    const float* __restrict__ s, const float* __restrict__ sgate1_w,
    const float* __restrict__ sgate1_b, const float* __restrict__ a,
    const float* __restrict__ lns, const float* __restrict__ s_w2,
    const float* __restrict__ scale_w2, const float* __restrict__ scale_b2,
    const float* __restrict__ shift_w2, const float* __restrict__ w1,
    const float* __restrict__ w2, const float* __restrict__ wout,
    const float* __restrict__ sgate2_w, const float* __restrict__ sgate2_b,
    float* __restrict__ out)
{
  __shared__ float srow[4][C_Sc], sn2[4][C_Sc];
  __shared__ float gor[4][C_Ac], ats[4][C_Ac], h2[4][C_Ac];
  __shared__ float gated[4][2*C_Ac];
  __shared__ float t1[4][C_Ac], t2[4][C_Ac], ta[4][C_Ac], tb[4][C_Ac];
  int n0 = blockIdx.x*4;
  int tid = threadIdx.x, w = tid>>6, lane = tid&63;

  for (int r=0;r<4;r++)
    for (int i=tid;i<C_Sc;i+=256){
      float sv = s[(size_t)(n0+r)*C_Sc+i];
      srow[r][i]=sv;
      sn2[r][i]=lns[(size_t)(n0+r)*C_Sc+i]*s_w2[i];
    }
  for (int f=tid; f<512; f+=256){ int r=f>>7, c=f&127; gor[r][c]=gows[(size_t)(n0+r)*C_Ac+c]; }
  __syncthreads();

  { // P1: sel0 -> out-proj x; sel1 -> sigmoid(s-gate1)
    int c = tid&127, sel = tid>>7;
    float acc[4];
    if (sel==0){
      #pragma unroll
      for (int r=0;r<4;r++) acc[r]=0.f;
      for (int i=0;i<C_Ac;i++){
        float wv=wo[(size_t)i*C_Ac+c];
        #pragma unroll
        for (int r=0;r<4;r++) acc[r]+=gor[r][i]*wv;
      }
      #pragma unroll
      for (int r=0;r<4;r++) t1[r][c]=acc[r];
    } else {
      #pragma unroll
      for (int r=0;r<4;r++) acc[r]=sgate1_b[c];
      for (int i=0;i<C_Sc;i++){
        float wv=sgate1_w[(size_t)i*C_Ac+c];
        #pragma unroll
        for (int r=0;r<4;r++) acc[r]+=srow[r][i]*wv;
      }
      #pragma unroll
      for (int r=0;r<4;r++) t2[r][c]=sigm(acc[r]);
    }
  }
  __syncthreads();
  for (int f=tid; f<512; f+=256){ int r=f>>7, c=f&127;
    ats[r][c] = t2[r][c]*t1[r][c] + a[(size_t)(n0+r)*C_Ac+c]; }
  __syncthreads();

  { // P2: LN(ats), row = wave; anv -> t1
    float v0=ats[w][lane], v1=ats[w][lane+64];
    float sx=v0+v1, sxx=v0*v0+v1*v1;
    #pragma unroll
    for (int off=32;off;off>>=1){ sx+=__shfl_xor(sx,off,64); sxx+=__shfl_xor(sxx,off,64); }
    float mean=sx*(1.f/C_Ac), rs=rsqrtf(sxx*(1.f/C_Ac)-mean*mean+1e-5f);
    t1[w][lane]=(v0-mean)*rs; t1[w][lane+64]=(v1-mean)*rs;
  }
  __syncthreads();

  { // P3: AdaLN2: sel0 -> ta = sigm(scale)*anv; sel1 -> tb = shift
    int c = tid&127, sel = tid>>7;
    float acc[4];
    const float* W = sel ? shift_w2 : scale_w2;
    #pragma unroll
    for (int r=0;r<4;r++) acc[r] = sel ? 0.f : scale_b2[c];
    for (int i=0;i<C_Sc;i++){
      float wv=W[(size_t)i*C_Ac+c];
      #pragma unroll
      for (int r=0;r<4;r++) acc[r]+=sn2[r][i]*wv;
    }
    if (sel==0){ 
      #pragma unroll
      for (int r=0;r<4;r++) ta[r][c]=sigm(acc[r])*t1[r][c];
    } else {
      #pragma unroll
      for (int r=0;r<4;r++) tb[r][c]=acc[r];
    }
  }
  __syncthreads();
  for (int f=tid; f<512; f+=256){ int r=f>>7, c=f&127; h2[r][c]=ta[r][c]+tb[r][c]; }
  __syncthreads();

  { // P4: SwiGLU hidden: thread owns col j of 256
    int j = tid;
    float a1[4], a2[4];
    #pragma unroll
    for (int r=0;r<4;r++){ a1[r]=0.f; a2[r]=0.f; }
    for (int i=0;i<C_Ac;i++){
      float w1v=w1[(size_t)i*2*C_Ac+j], w2v=w2[(size_t)i*2*C_Ac+j];
      #pragma unroll
      for (int r=0;r<4;r++){ float hv=h2[r][i]; a1[r]+=hv*w1v; a2[r]+=hv*w2v; }
    }
    #pragma unroll
    for (int r=0;r<4;r++) gated[r][j]=a1[r]*sigm(a1[r])*a2[r];
  }
  __syncthreads();

  { // P5: sel0 -> ff = gated@wout; sel1 -> sigmoid(s-gate2)
    int c = tid&127, sel = tid>>7;
    float acc[4];
    if (sel==0){
      #pragma unroll
      for (int r=0;r<4;r++) acc[r]=0.f;
      for (int j=0;j<2*C_Ac;j++){
        float wv=wout[(size_t)j*C_Ac+c];
        #pragma unroll
        for (int r=0;r<4;r++) acc[r]+=gated[r][j]*wv;
      }
      #pragma unroll
      for (int r=0;r<4;r++) t1[r][c]=acc[r];
    } else {
      #pragma unroll
      for (int r=0;r<4;r++) acc[r]=sgate2_b[c];
      for (int i=0;i<C_Sc;i++){
        float wv=sgate2_w[(size_t)i*C_Ac+c];
        #pragma unroll
        for (int r=0;r<4;r++) acc[r]+=srow[r][i]*wv;
      }
      #pragma unroll
      for (int r=0;r<4;r++) t2[r][c]=sigm(acc[r]);
    }
  }
  __syncthreads();
  for (int f=tid; f<512; f+=256){ int r=f>>7, c=f&127;
    out[(size_t)(n0+r)*C_Ac+c] = t2[r][c]*t1[r][c] + ats[r][c]; }
}

extern "C" void kernel_launch(void* const* d_in, const int* in_sizes, int n_in,
                              void* d_out, int out_size, void* d_ws, size_t ws_size,
                              hipStream_t stream)
{
  const float* a            = (const float*)d_in[0];
  const float* s            = (const float*)d_in[1];
  const float* z            = (const float*)d_in[2];
  const float* aln1_s_w     = (const float*)d_in[3];
  const float* aln1_scale_w = (const float*)d_in[4];
  const float* aln1_scale_b = (const float*)d_in[5];
  const float* aln1_shift_w = (const float*)d_in[6];
  const float* wq           = (const float*)d_in[7];
  const float* bq           = (const float*)d_in[8];
  const float* wk           = (const float*)d_in[9];
  const float* wv           = (const float*)d_in[10];
  const float* ln_z_w       = (const float*)d_in[11];
  const float* ln_z_b       = (const float*)d_in[12];
  const float* wb           = (const float*)d_in[13];
  const float* wg           = (const float*)d_in[14];
  const float* wo           = (const float*)d_in[15];
  const float* sgate1_w     = (const float*)d_in[16];
  const float* sgate1_b     = (const float*)d_in[17];
  const float* aln2_s_w     = (const float*)d_in[18];
  const float* aln2_scale_w = (const float*)d_in[19];
  const float* aln2_scale_b = (const float*)d_in[20];
  const float* aln2_shift_w = (const float*)d_in[21];
  const float* w1           = (const float*)d_in[22];
  const float* w2           = (const float*)d_in[23];
  const float* wout         = (const float*)d_in[24];
  const float* sgate2_w     = (const float*)d_in[25];
  const float* sgate2_b     = (const float*)d_in[26];
  float* out = (float*)d_out;

  float* ws   = (float*)d_ws;
  float* qws  = ws;                               // N*C_A
  float* kws  = qws  + (size_t)N_ATOMS*C_Ac;
  float* vws  = kws  + (size_t)N_ATOMS*C_Ac;
  float* gws  = vws  + (size_t)N_ATOMS*C_Ac;
  float* gows = gws  + (size_t)N_ATOMS*C_Ac;
  float* lns  = gows + (size_t)N_ATOMS*C_Ac;      // N*C_S
  float* part_m = lns + (size_t)N_ATOMS*C_Sc;     // KC*NQT*4*64
  float* part_l = part_m + (size_t)KC*NQT*4*64;
  float* part_o = part_l + (size_t)KC*NQT*4*64;   // KC*NQT*4*64*32

  hipLaunchKernelGGL(k_stage_a, dim3(N_ATOMS/4), dim3(256), 0, stream,
      a, s, aln1_s_w, aln1_scale_w, aln1_scale_b, aln1_shift_w,
      wq, bq, wk, wv, wg, qws, kws, vws, gws, lns);
  hipLaunchKernelGGL(k_attn, dim3(NQT, KC), dim3(256), 0, stream,
      z, ln_z_w, ln_z_b, wb, qws, kws, vws, part_m, part_l, part_o);
  hipLaunchKernelGGL(k_combine, dim3(NQT, 4), dim3(256), 0, stream,
      part_m, part_l, part_o, gws, gows);
  hipLaunchKernelGGL(k_stage_c, dim3(N_ATOMS/4), dim3(256), 0, stream,
      gows, wo, s, sgate1_w, sgate1_b, a, lns, aln2_s_w,
      aln2_scale_w, aln2_scale_b, aln2_shift_w, w1, w2, wout,
      sgate2_w, sgate2_b, out);
}